// Round 5
// baseline (130.470 us; speedup 1.0000x reference)
//
#include <hip/hip_runtime.h>
#include <hip/hip_bf16.h>

// Problem dims (fixed by the reference setup_inputs)
#define BB 8
#define TT 4096
#define SS 256
#define DD 512

typedef __attribute__((ext_vector_type(8))) short short8;
typedef __attribute__((ext_vector_type(4))) float floatx4;
typedef __attribute__((ext_vector_type(4))) int intx4;

// Packed RNE f32x2 -> bf16x2 (v_cvt_pk_bf16_f32 on gfx950).
__device__ inline int pk2(float a, float b) {
  __hip_bfloat162 h = __float22bfloat162_rn(make_float2(a, b));
  int r;
  __builtin_memcpy(&r, &h, 4);
  return r;
}

// Pack 8 consecutive-k f32 values into a bf16 MFMA fragment.
__device__ inline short8 cvt8(float4 f0, float4 f1) {
  intx4 p;
  p[0] = pk2(f0.x, f0.y);
  p[1] = pk2(f0.z, f0.w);
  p[2] = pk2(f1.x, f1.y);
  p[3] = pk2(f1.z, f1.w);
  return __builtin_bit_cast(short8, p);
}

__device__ inline float sq8(float4 f0, float4 f1) {
  return f0.x * f0.x + f0.y * f0.y + f0.z * f0.z + f0.w * f0.w +
         f1.x * f1.x + f1.y * f1.y + f1.z * f1.z + f1.w * f1.w;
}

// Fully fused cosine scorer:
//   C[b] = diag(1/||x||) * (bf16(X[b]) * bf16(Y[b])^T) * diag(1/||y||)
// Tile 64x128 (MxN), BK=64 f32: LDS = 16K (A) + 32K (B) + scales = 48.8 KB
// -> 3 blocks/CU (vs 2 with the 128x128 tile), grid 1024 -> 12 waves/CU.
// A/B staged RAW f32 via global_load_lds width=16; XOR-16 swizzle (LDS 16B
// slot s of a row holds logical block s ^ (row&15)) keeps ds_read_b128 frag
// reads bank-uniform. Row/col inverse norms accumulated in-tile during the
// frag-read phase, reduced via shfl_xor, applied in the epilogue.
__global__ __launch_bounds__(256) void cos_fused_kernel(
    const float* __restrict__ xs, const float* __restrict__ spk,
    float* __restrict__ out) {
  __shared__ float sA[64 * 64];
  __shared__ float sB[128 * 64];
  __shared__ float scX[64];
  __shared__ float scY[128];

  const int tid = threadIdx.x;
  const int wave = tid >> 6;
  const int lane = tid & 63;
  const int tn = blockIdx.x;  // 0..1  (N-tile of 128)
  const int tm = blockIdx.y;  // 0..63 (M-tile of 64)
  const int b = blockIdx.z;   // 0..7

  const float* Abase = xs + ((size_t)b * TT + tm * 64) * DD;
  const float* Bbase = spk + ((size_t)b * SS + tn * 128) * DD;

  floatx4 acc[2][4];
#pragma unroll
  for (int i = 0; i < 2; i++)
#pragma unroll
    for (int j = 0; j < 4; j++) acc[i][j] = (floatx4){0.f, 0.f, 0.f, 0.f};

  float sx[2] = {0.f, 0.f};
  float sy[4] = {0.f, 0.f, 0.f, 0.f};

  const int wm = wave >> 1;   // 0..1 -> rows wm*32..+32
  const int wn = wave & 1;    // 0..1 -> cols wn*64..+64
  const int quad = lane >> 4;
  const int l15 = lane & 15;

  // Staging maps (16B units, 16 units per row of 64 f32):
  // unit s: row = s>>4, slot = s&15 holds logical block (slot ^ (row&15)).
  int aoff[4], boff[8];
#pragma unroll
  for (int j = 0; j < 4; j++) {
    int s = j * 256 + tid;  // 1024 units: 64 rows
    int row = s >> 4;
    int blk = (s & 15) ^ (row & 15);
    aoff[j] = row * DD + blk * 4;
  }
#pragma unroll
  for (int j = 0; j < 8; j++) {
    int s = j * 256 + tid;  // 2048 units: 128 rows
    int row = s >> 4;
    int blk = (s & 15) ^ (row & 15);
    boff[j] = row * DD + blk * 4;
  }

  for (int kt = 0; kt < DD / 64; ++kt) {
#pragma unroll
    for (int j = 0; j < 4; j++) {
      const float* ga = Abase + aoff[j] + kt * 64;
      __builtin_amdgcn_global_load_lds(
          (const __attribute__((address_space(1))) unsigned int*)ga,
          (__attribute__((address_space(3))) unsigned int*)(sA +
              (j * 256 + wave * 64) * 4),
          16, 0, 0);
    }
#pragma unroll
    for (int j = 0; j < 8; j++) {
      const float* gb = Bbase + boff[j] + kt * 64;
      __builtin_amdgcn_global_load_lds(
          (const __attribute__((address_space(1))) unsigned int*)gb,
          (__attribute__((address_space(3))) unsigned int*)(sB +
              (j * 256 + wave * 64) * 4),
          16, 0, 0);
    }
    __syncthreads();

#pragma unroll
    for (int ks = 0; ks < 2; ks++) {
      short8 af[2], bf[4];
      const int b0 = ks * 8 + quad * 2;  // first 16B block of the frag's 8 f32
#pragma unroll
      for (int im = 0; im < 2; im++) {
        int row = wm * 32 + im * 16 + l15;
        int s0 = b0 ^ (row & 15);
        int s1 = (b0 + 1) ^ (row & 15);
        float4 f0 = *(const float4*)(sA + row * 64 + s0 * 4);
        float4 f1 = *(const float4*)(sA + row * 64 + s1 * 4);
        sx[im] += sq8(f0, f1);
        af[im] = cvt8(f0, f1);
      }
#pragma unroll
      for (int in = 0; in < 4; in++) {
        int row = wn * 64 + in * 16 + l15;
        int s0 = b0 ^ (row & 15);
        int s1 = (b0 + 1) ^ (row & 15);
        float4 f0 = *(const float4*)(sB + row * 64 + s0 * 4);
        float4 f1 = *(const float4*)(sB + row * 64 + s1 * 4);
        sy[in] += sq8(f0, f1);
        bf[in] = cvt8(f0, f1);
      }
#pragma unroll
      for (int im = 0; im < 2; im++)
#pragma unroll
        for (int in = 0; in < 4; in++)
          acc[im][in] = __builtin_amdgcn_mfma_f32_16x16x32_bf16(
              af[im], bf[in], acc[im][in], 0, 0, 0);
    }
    __syncthreads();
  }

  // Per-row sumsq: lanes {l15, l15+16, l15+32, l15+48} hold the 4
  // quad-partials of a row — butterfly over xor 16, 32. Waves with the same
  // wm (resp. wn) compute identical values; redundant stores are benign.
#pragma unroll
  for (int i = 0; i < 2; i++) {
    sx[i] += __shfl_xor(sx[i], 16, 64);
    sx[i] += __shfl_xor(sx[i], 32, 64);
  }
#pragma unroll
  for (int i = 0; i < 4; i++) {
    sy[i] += __shfl_xor(sy[i], 16, 64);
    sy[i] += __shfl_xor(sy[i], 32, 64);
  }
  if (quad == 0) {
#pragma unroll
    for (int i = 0; i < 2; i++)
      scX[wm * 32 + i * 16 + l15] = 1.0f / fmaxf(sqrtf(sx[i]), 1e-8f);
#pragma unroll
    for (int i = 0; i < 4; i++)
      scY[wn * 64 + i * 16 + l15] = 1.0f / fmaxf(sqrtf(sy[i]), 1e-8f);
  }
  __syncthreads();

  // Epilogue: C/D layout col = lane&15, row = quad*4 + reg; apply cosine
  // scales (dot * (1/||x||) * (1/||y||)).
  float* Obase = out + ((size_t)b * TT + tm * 64) * SS + tn * 128;
#pragma unroll
  for (int im = 0; im < 2; im++) {
#pragma unroll
    for (int in = 0; in < 4; in++) {
      int col = wn * 64 + in * 16 + l15;
      float yv = scY[col];
#pragma unroll
      for (int r = 0; r < 4; r++) {
        int row = wm * 32 + im * 16 + quad * 4 + r;
        Obase[row * SS + col] = acc[im][in][r] * scX[row] * yv;
      }
    }
  }
}

extern "C" void kernel_launch(void* const* d_in, const int* in_sizes, int n_in,
                              void* d_out, int out_size, void* d_ws,
                              size_t ws_size, hipStream_t stream) {
  const float* xs = (const float*)d_in[0];   // (8,4096,512) f32
  const float* spk = (const float*)d_in[1];  // (8,256,512) f32
  float* out = (float*)d_out;                // (8,4096,256) f32

  hipLaunchKernelGGL(cos_fused_kernel, dim3(SS / 128, TT / 64, BB), dim3(256),
                     0, stream, xs, spk, out);
}

// Round 6
// 122.203 us; speedup vs baseline: 1.0676x; 1.0676x over previous
//
#include <hip/hip_runtime.h>
#include <hip/hip_bf16.h>

// Problem dims (fixed by the reference setup_inputs)
#define BB 8
#define TT 4096
#define SS 256
#define DD 512

typedef __attribute__((ext_vector_type(8))) short short8;
typedef __attribute__((ext_vector_type(4))) float floatx4;
typedef __attribute__((ext_vector_type(4))) int intx4;

// Packed RNE f32x2 -> bf16x2 (v_cvt_pk_bf16_f32 on gfx950).
__device__ inline int pk2(float a, float b) {
  __hip_bfloat162 h = __float22bfloat162_rn(make_float2(a, b));
  int r;
  __builtin_memcpy(&r, &h, 4);
  return r;
}

// Pack 8 consecutive-k f32 values into a bf16 MFMA fragment.
__device__ inline short8 cvt8(float4 f0, float4 f1) {
  intx4 p;
  p[0] = pk2(f0.x, f0.y);
  p[1] = pk2(f0.z, f0.w);
  p[2] = pk2(f1.x, f1.y);
  p[3] = pk2(f1.z, f1.w);
  return __builtin_bit_cast(short8, p);
}

// Fully fused cosine scorer:
//   C[b] = diag(1/||x||) * (bf16(X[b]) * bf16(Y[b])^T) * diag(1/||y||)
// 128x128 tile, BK=64 f32, async global_load_lds width=16 staging with XOR-16
// swizzle (LDS 16B-slot s of a row holds logical block s ^ (row&15)) so
// ds_read_b128 frag reads are bank-uniform.
// Per-row sumsq comes from gram MFMAs: mfma(af,af) / mfma(bf,bf) — the 16x16
// diagonal is the sumsq of the fragment rows (A/B frag layouts are
// k-symmetric). wm==wn waves do A-grams, wm!=wn waves do B-grams (+4 MFMA
// per wave per kt, ~free at 7% MfmaUtil) replacing ~64 VALU FMAs. The frag
// loop is thus ds_read_b128 + packed-cvt + MFMA only.
__global__ __launch_bounds__(256) void cos_fused_kernel(
    const float* __restrict__ xs, const float* __restrict__ spk,
    float* __restrict__ out) {
  __shared__ float sA[128 * 64];
  __shared__ float sB[128 * 64];
  __shared__ float scX[128];
  __shared__ float scY[128];

  const int tid = threadIdx.x;
  const int wave = tid >> 6;
  const int lane = tid & 63;
  const int tn = blockIdx.x;  // 0..1
  const int tm = blockIdx.y;  // 0..31
  const int b = blockIdx.z;   // 0..7

  const float* Abase = xs + ((size_t)b * TT + tm * 128) * DD;
  const float* Bbase = spk + ((size_t)b * SS + tn * 128) * DD;

  floatx4 acc[4][4];
#pragma unroll
  for (int i = 0; i < 4; i++)
#pragma unroll
    for (int j = 0; j < 4; j++) acc[i][j] = (floatx4){0.f, 0.f, 0.f, 0.f};
  floatx4 accG[4];  // gram accumulators (A-rows if wm==wn else B-rows)
#pragma unroll
  for (int i = 0; i < 4; i++) accG[i] = (floatx4){0.f, 0.f, 0.f, 0.f};

  const int wm = wave >> 1;
  const int wn = wave & 1;
  const int quad = lane >> 4;
  const int l15 = lane & 15;
  const bool gramA = (wm == wn);

  // Staging map: 16B unit s = j*256 + tid; row = s>>4 (16 units/row);
  // slot = s&15 holds logical block (slot ^ (row&15)).
  int aoff[8];
#pragma unroll
  for (int j = 0; j < 8; j++) {
    int s = j * 256 + tid;
    int row = s >> 4;
    int blk = (s & 15) ^ (row & 15);
    aoff[j] = row * DD + blk * 4;
  }

  for (int kt = 0; kt < DD / 64; ++kt) {
#pragma unroll
    for (int j = 0; j < 8; j++) {
      const float* ga = Abase + aoff[j] + kt * 64;
      const float* gb = Bbase + aoff[j] + kt * 64;
      // wave-uniform LDS base; HW scatters lane i at base + i*16
      __builtin_amdgcn_global_load_lds(
          (const __attribute__((address_space(1))) unsigned int*)ga,
          (__attribute__((address_space(3))) unsigned int*)(sA +
              (j * 256 + wave * 64) * 4),
          16, 0, 0);
      __builtin_amdgcn_global_load_lds(
          (const __attribute__((address_space(1))) unsigned int*)gb,
          (__attribute__((address_space(3))) unsigned int*)(sB +
              (j * 256 + wave * 64) * 4),
          16, 0, 0);
    }
    __syncthreads();

#pragma unroll
    for (int ks = 0; ks < 2; ks++) {
      short8 af[4], bf[4];
      const int b0 = ks * 8 + quad * 2;  // first 16B block of the frag's 8 f32
#pragma unroll
      for (int im = 0; im < 4; im++) {
        int row = wm * 64 + im * 16 + l15;
        int s0 = b0 ^ (row & 15);
        int s1 = (b0 + 1) ^ (row & 15);
        float4 f0 = *(const float4*)(sA + row * 64 + s0 * 4);
        float4 f1 = *(const float4*)(sA + row * 64 + s1 * 4);
        af[im] = cvt8(f0, f1);
      }
#pragma unroll
      for (int in = 0; in < 4; in++) {
        int row = wn * 64 + in * 16 + l15;
        int s0 = b0 ^ (row & 15);
        int s1 = (b0 + 1) ^ (row & 15);
        float4 f0 = *(const float4*)(sB + row * 64 + s0 * 4);
        float4 f1 = *(const float4*)(sB + row * 64 + s1 * 4);
        bf[in] = cvt8(f0, f1);
      }
#pragma unroll
      for (int im = 0; im < 4; im++)
#pragma unroll
        for (int in = 0; in < 4; in++)
          acc[im][in] = __builtin_amdgcn_mfma_f32_16x16x32_bf16(
              af[im], bf[in], acc[im][in], 0, 0, 0);
      if (gramA) {
#pragma unroll
        for (int im = 0; im < 4; im++)
          accG[im] = __builtin_amdgcn_mfma_f32_16x16x32_bf16(
              af[im], af[im], accG[im], 0, 0, 0);
      } else {
#pragma unroll
        for (int in = 0; in < 4; in++)
          accG[in] = __builtin_amdgcn_mfma_f32_16x16x32_bf16(
              bf[in], bf[in], accG[in], 0, 0, 0);
      }
    }
    __syncthreads();
  }

  // Extract gram diagonals -> inverse norms. C/D layout: col = l15,
  // row = quad*4 + r; diagonal element d held by lane with l15 == d,
  // quad == d>>2, at reg r = d&3.
  if (quad == (l15 >> 2)) {
#pragma unroll
    for (int i = 0; i < 4; i++) {
      float inv = 1.0f / fmaxf(sqrtf(accG[i][l15 & 3]), 1e-8f);
      if (gramA)
        scX[wm * 64 + i * 16 + l15] = inv;  // waves (0,0),(1,1): rows 0..127
      else
        scY[wn * 64 + i * 16 + l15] = inv;  // waves (0,1),(1,0): cols 0..127
    }
  }
  __syncthreads();

  // Epilogue: apply cosine scales (dot * (1/||x||) * (1/||y||)).
  float* Obase = out + ((size_t)b * TT + tm * 128) * SS + tn * 128;
#pragma unroll
  for (int im = 0; im < 4; im++) {
#pragma unroll
    for (int in = 0; in < 4; in++) {
      int col = wn * 64 + in * 16 + l15;
      float yv = scY[col];
#pragma unroll
      for (int r = 0; r < 4; r++) {
        int row = wm * 64 + im * 16 + quad * 4 + r;
        Obase[row * SS + col] = acc[im][in][r] * scX[row] * yv;
      }
    }
  }
}

extern "C" void kernel_launch(void* const* d_in, const int* in_sizes, int n_in,
                              void* d_out, int out_size, void* d_ws,
                              size_t ws_size, hipStream_t stream) {
  const float* xs = (const float*)d_in[0];   // (8,4096,512) f32
  const float* spk = (const float*)d_in[1];  // (8,256,512) f32
  float* out = (float*)d_out;                // (8,4096,256) f32

  hipLaunchKernelGGL(cos_fused_kernel, dim3(SS / 128, TT / 128, BB), dim3(256),
                     0, stream, xs, spk, out);
}